// Round 6
// baseline (255.208 us; speedup 1.0000x reference)
//
#include <hip/hip_runtime.h>
#include <stdint.h>

typedef __attribute__((ext_vector_type(8))) __bf16 bf16x8;
typedef __attribute__((ext_vector_type(4))) __bf16 bf16x4;
typedef __attribute__((ext_vector_type(4))) float f32x4;

#define ATOMIC_ST(p, v) __hip_atomic_store((p), (v), __ATOMIC_RELAXED, __HIP_MEMORY_SCOPE_AGENT)
#define ATOMIC_LD(p)    __hip_atomic_load((p), __ATOMIC_RELAXED, __HIP_MEMORY_SCOPE_AGENT)

__device__ __forceinline__ void load16_to_lds(const __bf16* g, __bf16* l) {
  __builtin_amdgcn_global_load_lds(
      (const __attribute__((address_space(1))) void*)g,
      (__attribute__((address_space(3))) void*)l, 16, 0, 0);
}

// ws: totalbf @0 (4 MB) | sq @4194304 (32 KB) | scal @4227072 (64 B, [8]=cnt_sq [9]=cnt_gram)
//     part @4227136 (2080 f32) | pcol @4235456 (64x256 f32) | pss @4301056 (64 f32)

// ---------------- outs GEMM: tile 32(M) x 128(N), 512 blocks, reg-dbuf staging --
// NO atomics. waves 2x2: wave = 16M x 64N, acc[4] (16 regs). BK=64, 8 chunks.
__global__ __launch_bounds__(256) void k_outs(const float* __restrict__ x,
                                              const float* __restrict__ W,
                                              const float* __restrict__ bias,
                                              __bf16* __restrict__ totalbf) {
  __shared__ __bf16 As[32][72];
  __shared__ __bf16 Bs[128][72];
  const int bj = blockIdx.x;    // 0..3
  const int bi = blockIdx.y;    // 0..127
  const int t = threadIdx.x;
  const int wid = t >> 6, lane = t & 63;
  const int wr = wid >> 1, wc = wid & 1;
  const int n16 = lane & 15, q = lane >> 4;

  const int arow0 = bi * 32;
  const int brow0 = bj * 128;
  const int rA = t >> 3, cA = (t & 7) * 8;

  f32x4 acc[4];
  f32x4 zero = {0.f, 0.f, 0.f, 0.f};
  for (int j = 0; j < 4; ++j) acc[j] = zero;

  float4 ar[2];
  float4 br[4][2];
  {
    const float* pa = x + (size_t)(arow0 + rA) * 512 + cA;
    ar[0] = *(const float4*)(pa);
    ar[1] = *(const float4*)(pa + 4);
    for (int p = 0; p < 4; ++p) {
      const float* pb = W + (size_t)(brow0 + p * 32 + rA) * 512 + cA;
      br[p][0] = *(const float4*)(pb);
      br[p][1] = *(const float4*)(pb + 4);
    }
  }

  for (int kc = 0; kc < 8; ++kc) {
    __syncthreads();
    {
      bf16x8 va = {(__bf16)ar[0].x, (__bf16)ar[0].y, (__bf16)ar[0].z, (__bf16)ar[0].w,
                   (__bf16)ar[1].x, (__bf16)ar[1].y, (__bf16)ar[1].z, (__bf16)ar[1].w};
      *(bf16x8*)&As[rA][cA] = va;
      for (int p = 0; p < 4; ++p) {
        bf16x8 vb = {(__bf16)br[p][0].x, (__bf16)br[p][0].y, (__bf16)br[p][0].z, (__bf16)br[p][0].w,
                     (__bf16)br[p][1].x, (__bf16)br[p][1].y, (__bf16)br[p][1].z, (__bf16)br[p][1].w};
        *(bf16x8*)&Bs[p * 32 + rA][cA] = vb;
      }
    }
    if (kc < 7) {
      const float* pa = x + (size_t)(arow0 + rA) * 512 + (kc + 1) * 64 + cA;
      ar[0] = *(const float4*)(pa);
      ar[1] = *(const float4*)(pa + 4);
      for (int p = 0; p < 4; ++p) {
        const float* pb = W + (size_t)(brow0 + p * 32 + rA) * 512 + (kc + 1) * 64 + cA;
        br[p][0] = *(const float4*)(pb);
        br[p][1] = *(const float4*)(pb + 4);
      }
    }
    __syncthreads();
    for (int ks = 0; ks < 2; ++ks) {
      bf16x8 af = *(const bf16x8*)&As[wr * 16 + n16][ks * 32 + q * 8];
      for (int fc = 0; fc < 4; ++fc) {
        bf16x8 bfr = *(const bf16x8*)&Bs[wc * 64 + fc * 16 + n16][ks * 32 + q * 8];
        acc[fc] = __builtin_amdgcn_mfma_f32_16x16x32_bf16(af, bfr, acc[fc], 0, 0, 0);
      }
    }
  }

  // epilogue: +bias, bf16 store. Nothing else.
  const int l = bj >> 1, oc0 = (bj & 1) * 128;
  for (int fc = 0; fc < 4; ++fc) {
    float bv = bias[bj * 128 + wc * 64 + fc * 16 + n16];
    int o = oc0 + wc * 64 + fc * 16 + n16;
    for (int r = 0; r < 4; ++r) {
      int mrow = arow0 + wr * 16 + q * 4 + r;
      totalbf[(size_t)(l * 4096 + mrow) * 256 + o] = (__bf16)(acc[fc][r] + bv);
    }
  }
}

// ---------------- k_sq: row sq + colsum + bandwidth, atomic-free ---------------
// 64 blocks x 256 thr; block b handles rows b*128..+128 (wave w: rows it*4+w).
__global__ __launch_bounds__(256) void k_sq(const __bf16* __restrict__ tot,
                                            float* __restrict__ sq,
                                            float* __restrict__ scal,
                                            float* __restrict__ pcol,
                                            float* __restrict__ pss) {
  __shared__ float lcol[4][256];
  __shared__ float red[256];
  __shared__ int lastflag;
  const int t = threadIdx.x;
  const int wave = t >> 6, lane = t & 63;
  float c0 = 0.f, c1 = 0.f, c2 = 0.f, c3 = 0.f, ssum = 0.f;
  for (int it = 0; it < 32; ++it) {
    int row = blockIdx.x * 128 + it * 4 + wave;
    bf16x4 v = *(const bf16x4*)(tot + (size_t)row * 256 + lane * 4);
    float f0 = v[0], f1 = v[1], f2 = v[2], f3 = v[3];
    float s = f0 * f0 + f1 * f1 + f2 * f2 + f3 * f3;
    for (int off = 1; off < 64; off <<= 1) s += __shfl_xor(s, off, 64);
    if (lane == 0) { sq[row] = s; ssum += s; }
    c0 += f0; c1 += f1; c2 += f2; c3 += f3;
  }
  lcol[wave][lane * 4 + 0] = c0;
  lcol[wave][lane * 4 + 1] = c1;
  lcol[wave][lane * 4 + 2] = c2;
  lcol[wave][lane * 4 + 3] = c3;
  red[t] = (lane == 0) ? ssum : 0.f;
  __syncthreads();
  ATOMIC_ST(&pcol[blockIdx.x * 256 + t], lcol[0][t] + lcol[1][t] + lcol[2][t] + lcol[3][t]);
  if (t == 0) ATOMIC_ST(&pss[blockIdx.x], red[0] + red[64] + red[128] + red[192]);
  __threadfence();
  __syncthreads();
  if (t == 0) lastflag = (atomicAdd((int*)&scal[8], 1) == 63);
  __syncthreads();
  if (lastflag) {
    __threadfence();
    float cs = 0.f;
    for (int b = 0; b < 64; ++b) cs += ATOMIC_LD(&pcol[b * 256 + t]);
    float contrib = -2.f * cs * cs;                       // -2*||colsum||^2 part
    if (t < 64) contrib += 16384.f * ATOMIC_LD(&pss[t]);  // 2n*sumsq part
    red[t] = contrib;
    __syncthreads();
    for (int off = 128; off; off >>= 1) { if (t < off) red[t] += red[t + off]; __syncthreads(); }
    if (t == 0) {
      double sumdist = (double)red[0];
      double bw = sumdist / (8192.0 * 8192.0 - 8192.0) / 4.0;  // / KERNEL_MUL^(5//2)
      scal[1] = (float)(1.4426950408889634 / (bw * 16.0));     // g4 * log2(e)
    }
  }
}

// ---------------- combine with fused gates: one wave per row ------------------
__global__ __launch_bounds__(256) void k_combine(const float* __restrict__ x,
                                                 const float* __restrict__ Waux,
                                                 const float* __restrict__ baux,
                                                 const __bf16* __restrict__ tot,
                                                 float* __restrict__ out) {
  const int wid = threadIdx.x >> 6;
  const int lane = threadIdx.x & 63;
  const int row = blockIdx.x * 4 + wid;
  const float4* xr = (const float4*)(x + (size_t)row * 512);
  const float4* w0 = (const float4*)(Waux);
  const float4* w1 = (const float4*)(Waux + 512);
  float p0 = 0.f, p1 = 0.f;
  for (int c = lane; c < 128; c += 64) {
    float4 xv = xr[c];
    float4 a = w0[c], b = w1[c];
    p0 += xv.x * a.x + xv.y * a.y + xv.z * a.z + xv.w * a.w;
    p1 += xv.x * b.x + xv.y * b.y + xv.z * b.z + xv.w * b.w;
  }
  for (int off = 1; off < 64; off <<= 1) {
    p0 += __shfl_xor(p0, off, 64);
    p1 += __shfl_xor(p1, off, 64);
  }
  p0 += baux[0]; p1 += baux[1];
  float m = fmaxf(p0, p1);
  float e0 = __expf(p0 - m), e1 = __expf(p1 - m);
  float inv = 1.f / (e0 + e1);
  float g0 = e0 * inv, g1 = e1 * inv;

  int oc = lane * 4;
  bf16x4 v0 = *(const bf16x4*)(tot + (size_t)row * 256 + oc);
  bf16x4 v1 = *(const bf16x4*)(tot + (size_t)(4096 + row) * 256 + oc);
  float4 r;
  r.x = g0 * (float)v0[0] + g1 * (float)v1[0];
  r.y = g0 * (float)v0[1] + g1 * (float)v1[1];
  r.z = g0 * (float)v0[2] + g1 * (float)v1[2];
  r.w = g0 * (float)v0[3] + g1 * (float)v1[3];
  *(float4*)(out + (size_t)row * 256 + oc) = r;
}

// ---------------- Gram + fused kernel sum: BK=64 dbuf DMA, atomic-free tail ----
// 2080 triangular 128x128 tiles. LDS chunk = 128 rows x 64 cols (128 B rows,
// 8 slots of 16 B); slot s holds col chunk s^(row&7)  [R2-verified 0-conflict].
__global__ __launch_bounds__(256) void k_gram(const __bf16* __restrict__ tot,
                                              const float* __restrict__ sq,
                                              const float* __restrict__ scal,
                                              float* __restrict__ part,
                                              float* __restrict__ out) {
  __shared__ __bf16 As[2][128 * 64];   // 2 x 16 KB
  __shared__ __bf16 Bs[2][128 * 64];
  __shared__ float sqi[128], sqj[128];
  __shared__ float wred[4];
  __shared__ int lastflag;
  const int t = threadIdx.x;
  const int wid = t >> 6, lane = t & 63;
  const int wr = wid >> 1, wc = wid & 1;
  const int n16 = lane & 15, q = lane >> 4;

  // triangular decode: blockIdx.x -> (ti, tj), ti <= tj
  int m = 2079 - (int)blockIdx.x;
  int n = (int)((sqrtf(8.f * (float)m + 1.f) - 1.f) * 0.5f);
  while ((n + 1) * (n + 2) / 2 <= m) ++n;
  while (n * (n + 1) / 2 > m) --n;
  const int ti = 63 - n;
  const int tj = 63 - (m - n * (n + 1) / 2);

  // DMA: wave handles segments wid*4..wid*4+3 (segment = 8 rows x 1 KB LDS).
  // lane: row-in-seg lrow = lane>>3, slot = lane&7, source col chunk = slot^lrow.
  const int lrow = lane >> 3;
  const int scol = ((lane & 7) ^ lrow) * 8;      // elems within 64-elem chunk row
  const int seg0 = wid * 4;
  const __bf16* gA = tot + (size_t)(ti * 128) * 256 + (size_t)lrow * 256 + scol;
  const __bf16* gB = tot + (size_t)(tj * 128) * 256 + (size_t)lrow * 256 + scol;

  if (t < 128) sqi[t] = sq[ti * 128 + t];
  else         sqj[t - 128] = sq[tj * 128 + (t - 128)];

  f32x4 acc[4][4];
  f32x4 zero = {0.f, 0.f, 0.f, 0.f};
  for (int i = 0; i < 4; ++i)
    for (int j = 0; j < 4; ++j) acc[i][j] = zero;

  // prologue: DMA chunk 0 -> buf 0
  for (int s = 0; s < 4; ++s) {
    int seg = seg0 + s;
    load16_to_lds(gA + (size_t)(seg * 8) * 256, &As[0][seg * 512]);
    load16_to_lds(gB + (size_t)(seg * 8) * 256, &Bs[0][seg * 512]);
  }

  for (int kc = 0; kc < 4; ++kc) {
    __syncthreads();   // drains chunk kc DMA; prior readers of the other buf done
    if (kc < 3) {
      const int nb = (kc + 1) & 1;
      const int off = (kc + 1) * 64;
      for (int s = 0; s < 4; ++s) {
        int seg = seg0 + s;
        load16_to_lds(gA + (size_t)(seg * 8) * 256 + off, &As[nb][seg * 512]);
        load16_to_lds(gB + (size_t)(seg * 8) * 256 + off, &Bs[nb][seg * 512]);
      }
    }
    const int cb = kc & 1;
    for (int ks = 0; ks < 2; ++ks) {
      bf16x8 af[4], bfr[4];
      for (int f = 0; f < 4; ++f) {
        int ra = wr * 64 + f * 16 + n16;
        af[f] = *(const bf16x8*)&As[cb][ra * 64 + (((ks * 4 + q) ^ (ra & 7)) * 8)];
        int rb = wc * 64 + f * 16 + n16;
        bfr[f] = *(const bf16x8*)&Bs[cb][rb * 64 + (((ks * 4 + q) ^ (rb & 7)) * 8)];
      }
      for (int fr = 0; fr < 4; ++fr)
        for (int fc = 0; fc < 4; ++fc)
          acc[fr][fc] = __builtin_amdgcn_mfma_f32_16x16x32_bf16(af[fr], bfr[fc], acc[fr][fc], 0, 0, 0);
    }
  }

  // epilogue: u = exp2(fma(2g, dot, -g*(si+sj))); ksum = u+u^2+u^4+u^8+u^16
  const float g = scal[1];
  const float g2 = 2.f * g;
  float cj[4];
  for (int fc = 0; fc < 4; ++fc)
    cj[fc] = -g * sqj[wc * 64 + fc * 16 + n16];

  float lsum = 0.f;
  for (int fr = 0; fr < 4; ++fr) {
    for (int r = 0; r < 4; ++r) {
      float ci = -g * sqi[wr * 64 + fr * 16 + q * 4 + r];
      for (int fc = 0; fc < 4; ++fc) {
        float p = fmaf(g2, acc[fr][fc][r], ci + cj[fc]);
        float u = exp2f(p);
        float u2 = u * u, u4 = u2 * u2, u8 = u4 * u4, u16 = u8 * u8;
        lsum += ((u + u2) + (u4 + u8)) + u16;
      }
    }
  }
  for (int off = 1; off < 64; off <<= 1) lsum += __shfl_xor(lsum, off, 64);
  if (lane == 0) wred[wid] = lsum;
  __syncthreads();
  if (t == 0) {
    float blocksum = wred[0] + wred[1] + wred[2] + wred[3];
    float sgn = ((ti < 32) == (tj < 32)) ? 1.f : -1.f;
    float wgt = (ti == tj) ? sgn : 2.f * sgn;
    ATOMIC_ST(&part[blockIdx.x], wgt * blocksum);   // distinct slot, native store
  }
  __threadfence();
  __syncthreads();
  if (t == 0) lastflag = (atomicAdd((int*)(part - 7), 1) == 2079);  // scal[9]
  __syncthreads();
  if (lastflag) {
    __threadfence();
    float s = 0.f;
    for (int i = t; i < 2080; i += 256) s += ATOMIC_LD(&part[i]);
    float* red = (float*)As;   // reuse LDS
    red[t] = s;
    __syncthreads();
    for (int off = 128; off; off >>= 1) { if (t < off) red[t] += red[t + off]; __syncthreads(); }
    if (t == 0) out[1048576] = -(red[0] / 16777216.0f);
  }
}

extern "C" void kernel_launch(void* const* d_in, const int* in_sizes, int n_in,
                              void* d_out, int out_size, void* d_ws, size_t ws_size,
                              hipStream_t stream) {
  const float* x    = (const float*)d_in[0];
  const float* Waux = (const float*)d_in[1];
  const float* baux = (const float*)d_in[2];
  const float* W    = (const float*)d_in[3];
  const float* bias = (const float*)d_in[4];
  float* out = (float*)d_out;

  char* ws = (char*)d_ws;
  __bf16* totalbf = (__bf16*)ws;                    // 4,194,304 B
  float* sq   = (float*)(ws + 4194304);             // 8192 f32 (plain stores)
  float* scal = (float*)(ws + 4227072);             // 16 f32; [8],[9] = int counters
  float* part = (float*)(ws + 4227136);             // 2080 f32 (k_gram partials)
  float* pcol = (float*)(ws + 4235456);             // 64*256 f32 (k_sq col partials)
  float* pss  = (float*)(ws + 4301056);             // 64 f32 (k_sq sumsq partials)
  // k_gram derives its counter as (int*)(part - 7) == &scal[9]. Keep layout in sync.

  // only the counters/scalars need zeroing (everything else is store-then-read)
  hipMemsetAsync(ws + 4227072, 0, 64, stream);

  k_outs<<<dim3(4, 128), 256, 0, stream>>>(x, W, bias, totalbf);
  k_sq<<<64, 256, 0, stream>>>(totalbf, sq, scal, pcol, pss);
  k_combine<<<1024, 256, 0, stream>>>(x, Waux, baux, totalbf, out);
  k_gram<<<2080, 256, 0, stream>>>(totalbf, sq, scal, part, out);
}